// Round 1
// baseline (12.554 us; speedup 1.0000x reference)
//
#include <hip/hip_runtime.h>

// StructuredPerceptron: B=32, S=2048, T=512
// loss = sum_b max(pred_score_b - gold_score_b, 0)
// score = sum_{s<L} unary[b,s,tag[s]] + sum_{1<=s<L} binary[tag[s-1],tag[s]]
// where L = sum_s mask[b,s]  (prefix-length semantics, per reference)

#define BB 32
#define SS 2048
#define TT 512

__global__ __launch_bounds__(256) void sp_batch_kernel(
    const float* __restrict__ unary,
    const float* __restrict__ binary,
    const int*   __restrict__ tags,
    const int*   __restrict__ pred,
    const int*   __restrict__ mask,
    float*       __restrict__ ws)
{
    const int b   = blockIdx.x;
    const int tid = threadIdx.x;
    const int wave = tid >> 6;

    __shared__ int   s_ipart[4];
    __shared__ float s_part[8];
    __shared__ int   s_len;

    // ---- seq_len = sum(mask[b, :]) ----
    int m = 0;
    for (int s = tid; s < SS; s += 256) m += mask[b * SS + s];
    #pragma unroll
    for (int off = 32; off > 0; off >>= 1) m += __shfl_down(m, off);
    if ((tid & 63) == 0) s_ipart[wave] = m;
    __syncthreads();
    if (tid == 0) s_len = s_ipart[0] + s_ipart[1] + s_ipart[2] + s_ipart[3];
    __syncthreads();
    const int L = s_len;

    // ---- gold / pred scores ----
    float g = 0.f, p = 0.f;
    for (int s = tid; s < SS; s += 256) {
        if (s < L) {
            const int base = b * SS + s;
            const int tg = tags[base];
            const int tp = pred[base];
            g += unary[base * TT + tg];
            p += unary[base * TT + tp];
            if (s >= 1) {
                const int tg0 = tags[base - 1];
                const int tp0 = pred[base - 1];
                g += binary[tg0 * TT + tg];
                p += binary[tp0 * TT + tp];
            }
        }
    }
    #pragma unroll
    for (int off = 32; off > 0; off >>= 1) {
        g += __shfl_down(g, off);
        p += __shfl_down(p, off);
    }
    if ((tid & 63) == 0) { s_part[wave * 2] = g; s_part[wave * 2 + 1] = p; }
    __syncthreads();
    if (tid == 0) {
        const float G = s_part[0] + s_part[2] + s_part[4] + s_part[6];
        const float P = s_part[1] + s_part[3] + s_part[5] + s_part[7];
        ws[b] = fmaxf(P - G, 0.f);
    }
}

__global__ __launch_bounds__(64) void sp_final_kernel(
    const float* __restrict__ ws, float* __restrict__ out)
{
    const int tid = threadIdx.x;
    float v = (tid < BB) ? ws[tid] : 0.f;
    #pragma unroll
    for (int off = 32; off > 0; off >>= 1) v += __shfl_down(v, off);
    if (tid == 0) out[0] = v;
}

extern "C" void kernel_launch(void* const* d_in, const int* in_sizes, int n_in,
                              void* d_out, int out_size, void* d_ws, size_t ws_size,
                              hipStream_t stream) {
    const float* unary  = (const float*)d_in[0];
    const float* binary = (const float*)d_in[1];
    const int*   tags   = (const int*)d_in[2];
    const int*   pred   = (const int*)d_in[3];
    const int*   mask   = (const int*)d_in[4];
    float* ws  = (float*)d_ws;
    float* out = (float*)d_out;

    sp_batch_kernel<<<BB, 256, 0, stream>>>(unary, binary, tags, pred, mask, ws);
    sp_final_kernel<<<1, 64, 0, stream>>>(ws, out);
}